// Round 6
// baseline (6650.261 us; speedup 1.0000x reference)
//
#include <hip/hip_runtime.h>

// Problem constants
#define NB 8
#define NT 1024
#define ND 768     // = 12*64
#define NH 12
#define NU 64
#define BT (NB*NT)   // 8192
#define SCALE32 ((float)0.03608439182435161)  // fp32(768^-0.5)
#define EPS32 1e-7f

// ---------------------------------------------------------------------------
// ALL-NAMED-REGISTER dot64: R5 lesson — qr[64] written via float4-pointer
// cast is scratch-demoted (VGPR_Count=52, 64 scratch reads/dot). Zero local
// arrays in hot loops: q = qq0..qq15, K row = kk0..kk15, all named float4.
// Op sequence identical to numpy SSE2 dot64_np: 4 accumulators stride-4
// (init i=0, adds i=1..15, each mul/add individually rounded), reduce
// (r0+r2)+(r1+r3). BITWISE-IDENTICAL.
// ---------------------------------------------------------------------------
#define QLOADALL \
    const float4 qq0=qp[0],  qq1=qp[1],  qq2=qp[2],  qq3=qp[3], \
                 qq4=qp[4],  qq5=qp[5],  qq6=qp[6],  qq7=qp[7], \
                 qq8=qp[8],  qq9=qp[9],  qq10=qp[10],qq11=qp[11], \
                 qq12=qp[12],qq13=qp[13],qq14=qp[14],qq15=qp[15];

#define KLOADALL \
    const float4 kk0=kp[0],  kk1=kp[1],  kk2=kp[2],  kk3=kp[3], \
                 kk4=kp[4],  kk5=kp[5],  kk6=kp[6],  kk7=kp[7], \
                 kk8=kp[8],  kk9=kp[9],  kk10=kp[10],kk11=kp[11], \
                 kk12=kp[12],kk13=kp[13],kk14=kp[14],kk15=kp[15];

#define DOT_ACC(i) \
    r0 = __fadd_rn(r0, __fmul_rn(qq##i.x, kk##i.x)); \
    r1 = __fadd_rn(r1, __fmul_rn(qq##i.y, kk##i.y)); \
    r2 = __fadd_rn(r2, __fmul_rn(qq##i.z, kk##i.z)); \
    r3 = __fadd_rn(r3, __fmul_rn(qq##i.w, kk##i.w));

#define DOT16(dt) \
    float r0 = __fmul_rn(qq0.x, kk0.x); \
    float r1 = __fmul_rn(qq0.y, kk0.y); \
    float r2 = __fmul_rn(qq0.z, kk0.z); \
    float r3 = __fmul_rn(qq0.w, kk0.w); \
    DOT_ACC(1)  DOT_ACC(2)  DOT_ACC(3)  DOT_ACC(4)  DOT_ACC(5) \
    DOT_ACC(6)  DOT_ACC(7)  DOT_ACC(8)  DOT_ACC(9)  DOT_ACC(10) \
    DOT_ACC(11) DOT_ACC(12) DOT_ACC(13) DOT_ACC(14) DOT_ACC(15) \
    const float dt = __fadd_rn(__fadd_rn(r0, r2), __fadd_rn(r1, r3));

// ---------------------------------------------------------------------------
// Mask decode with byte/int32 layout sniff (mask is all-ones in practice).
// ---------------------------------------------------------------------------
__global__ __launch_bounds__(256) void mask_k(
    const unsigned char* __restrict__ mb, float* __restrict__ mf)
{
    __shared__ int cntOff, cntAll;
    if (threadIdx.x == 0) { cntOff = 0; cntAll = 0; }
    __syncthreads();
    int lo = 0, la = 0;
    for (int i = threadIdx.x; i < BT; i += 256)
        if (mb[i] != 0) { la++; if ((i & 3) != 0) lo++; }
    atomicAdd(&cntOff, lo);
    atomicAdd(&cntAll, la);
    __syncthreads();
    const bool int32mode = (cntOff == 0) && (cntAll != 0);
    if (int32mode) {
        const int* mi = (const int*)mb;
        for (int i = threadIdx.x; i < BT; i += 256)
            mf[i] = (mi[i] != 0) ? 1.f : 0.f;
    } else {
        for (int i = threadIdx.x; i < BT; i += 256)
            mf[i] = (mb[i] != 0) ? 1.f : 0.f;
    }
}

// ---------------------------------------------------------------------------
// OpenBLAS-mimic sgemm: C = A[8192x768] @ W[768x768] (+R elementwise after).
// kc=384 panel split preserved bitwise. grid (128,12). Unchanged.
// ---------------------------------------------------------------------------
__global__ __launch_bounds__(256) void gemmseq(
    const float* __restrict__ A, const float* __restrict__ W,
    const float* __restrict__ R, float* __restrict__ C)
{
    __shared__ float sA[64][68];   // [k][m], transposed, pad 68 (16B-aligned rows)
    __shared__ float sB[64][68];   // [k][n]

    const int t = threadIdx.x;
    const int mbase = blockIdx.x * 64;
    const int nbase = blockIdx.y * 64;
    const int m0 = (t >> 4) * 4;
    const int n0 = (t & 15) * 4;

    float acc[4][4], accA[4][4];
#pragma unroll
    for (int i = 0; i < 4; i++)
#pragma unroll
        for (int j = 0; j < 4; j++) { acc[i][j] = 0.f; accA[i][j] = 0.f; }

    for (int k0 = 0; k0 < 768; k0 += 64) {
        __syncthreads();
#pragma unroll
        for (int i = 0; i < 4; i++) {
            const int idx = t + i * 256;          // 0..1023
            const int mr = idx >> 4;              // 0..63
            const int k4 = (idx & 15) * 4;        // 0..60
            const float4 a4 = *(const float4*)&A[(size_t)(mbase + mr) * 768 + k0 + k4];
            sA[k4 + 0][mr] = a4.x;
            sA[k4 + 1][mr] = a4.y;
            sA[k4 + 2][mr] = a4.z;
            sA[k4 + 3][mr] = a4.w;
            *(float4*)&sB[mr][k4] =
                *(const float4*)&W[(size_t)(k0 + mr) * 768 + nbase + k4];
        }
        __syncthreads();

        for (int kk = 0; kk < 64; kk++) {
            float av[4], bv[4];
            *(float4*)&av[0] = *(const float4*)&sA[kk][m0];
            *(float4*)&bv[0] = *(const float4*)&sB[kk][n0];
#pragma unroll
            for (int i = 0; i < 4; i++)
#pragma unroll
                for (int j = 0; j < 4; j++)
                    acc[i][j] = fmaf(av[i], bv[j], acc[i][j]);
        }

        if (k0 + 64 == 384) {   // end of first kc panel (OpenBLAS kc=384)
#pragma unroll
            for (int i = 0; i < 4; i++)
#pragma unroll
                for (int j = 0; j < 4; j++) {
                    accA[i][j] = acc[i][j];
                    acc[i][j] = 0.f;
                }
        }
    }

#pragma unroll
    for (int i = 0; i < 4; i++)
#pragma unroll
        for (int j = 0; j < 4; j++) {
            const size_t idx = (size_t)(mbase + m0 + i) * 768 + nbase + n0 + j;
            float o = __fadd_rn(accA[i][j], acc[i][j]);  // C = panel0 + panel1
            if (R) o = __fadd_rn(o, R[idx]);             // np: out = tmp + x
            C[idx] = o;
        }
}

// ---------------------------------------------------------------------------
// Denominator: one THREAD per row; q in 16 named float4 VGPRs; K row in
// 16 named float4 per step (vector path, wave-uniform addr = 1 broadcast
// line/load). b8 chains = 8 NAMED floats, k=0 peeled as init (s-ascending
// per chain, identical to serial s<8-init / s>=8-add). Bi[8] array is
// cold scratch (16 accesses/thread). launch_bounds(128,2): cap 256 VGPR.
// grid 768 x 128, XCD-swizzled. Arithmetic bitwise-identical to R9.
// ---------------------------------------------------------------------------
#define DEN_STEP(j, kexpr, INIT) { \
    const int sg = c * 128 + (kexpr) * 8 + (j); \
    const float4* kp = (const float4*)(Kb + (size_t)sg * ND); \
    KLOADALL \
    DOT16(dt) \
    float sc = __fmul_rn(dt, SCALE32); \
    sc = __fmul_rn(sc, MFb[sg]); \
    sc = __fmul_rn(sc, mq); \
    if (INIT) b8_##j = sc; \
    else      b8_##j = __fadd_rn(b8_##j, sc); \
}

__global__ __launch_bounds__(128, 2) void denom_np(
    const float* __restrict__ Q, const float* __restrict__ K,
    const float* __restrict__ MF, float* __restrict__ D)
{
    const int bid = blockIdx.x;
    const int lb  = (bid & 7) * 96 + (bid >> 3);     // XCD-grouped logical id
    const int gid = lb * 128 + threadIdx.x;          // 0..98303
    const int bh = gid >> 10;                        // uniform per block
    const int row = gid & 1023;
    const int b = bh / NH, h = bh % NH;
    const int bh_u = __builtin_amdgcn_readfirstlane(bh);
    const int b_u = bh_u / NH;

    const float mq = MF[b * NT + row];

    const float4* qp = (const float4*)&Q[((size_t)(b * NT + row)) * ND + h * 64];
    QLOADALL

    const float* Kb = &K[((size_t)(b * NT)) * ND + h * 64];
    const float* MFb = &MF[b_u * NT];                // scalar path

    float Bi[8];
    for (int c = 0; c < 8; c++) {
        float b8_0, b8_1, b8_2, b8_3, b8_4, b8_5, b8_6, b8_7;
        // k = 0: init (s = c*128 + 0..7)
        DEN_STEP(0, 0, 1) DEN_STEP(1, 0, 1) DEN_STEP(2, 0, 1) DEN_STEP(3, 0, 1)
        DEN_STEP(4, 0, 1) DEN_STEP(5, 0, 1) DEN_STEP(6, 0, 1) DEN_STEP(7, 0, 1)
        for (int k = 1; k < 16; k++) {
            DEN_STEP(0, k, 0) DEN_STEP(1, k, 0) DEN_STEP(2, k, 0) DEN_STEP(3, k, 0)
            DEN_STEP(4, k, 0) DEN_STEP(5, k, 0) DEN_STEP(6, k, 0) DEN_STEP(7, k, 0)
        }
        Bi[c] = __fadd_rn(
            __fadd_rn(__fadd_rn(b8_0, b8_1), __fadd_rn(b8_2, b8_3)),
            __fadd_rn(__fadd_rn(b8_4, b8_5), __fadd_rn(b8_6, b8_7)));
    }

    D[(size_t)bh * NT + row] = __fadd_rn(
        __fadd_rn(__fadd_rn(Bi[0], Bi[1]), __fadd_rn(Bi[2], Bi[3])),
        __fadd_rn(__fadd_rn(Bi[4], Bi[5]), __fadd_rn(Bi[6], Bi[7])));
}

// ---------------------------------------------------------------------------
// Attention out: one THREAD per row; q = qq0..15, o = oo0..15 (named float4
// accumulators), K row = kk0..15 per iteration — ZERO local arrays, nothing
// scratch-demotable. V + MF on the scalar path (SMEM pipe overlaps the K
// vmem loads; SGPR file holds the V row with K off it). o[j] chains over s
// ascending 0..1023, per-op rounding identical to R9. Self-aliased QA.
// launch_bounds(128,2): cap 256 VGPR (qq64 + oo64 + kk64 + temps ~ 220).
// grid 768 x 128, XCD-swizzled.
// ---------------------------------------------------------------------------
#define AXPY(i) \
    oo##i.x = __fadd_rn(oo##i.x, __fmul_rn(p, vp[4*(i)+0])); \
    oo##i.y = __fadd_rn(oo##i.y, __fmul_rn(p, vp[4*(i)+1])); \
    oo##i.z = __fadd_rn(oo##i.z, __fmul_rn(p, vp[4*(i)+2])); \
    oo##i.w = __fadd_rn(oo##i.w, __fmul_rn(p, vp[4*(i)+3]));

__global__ __launch_bounds__(128, 2) void attn_np(
    const float* __restrict__ K, const float* __restrict__ V,
    const float* __restrict__ D, const float* __restrict__ MF,
    float* __restrict__ QA)   // in: Q, out: A (self-aliased per row)
{
    const int bid = blockIdx.x;
    const int lb  = (bid & 7) * 96 + (bid >> 3);     // XCD-grouped logical id
    const int gid = lb * 128 + threadIdx.x;
    const int bh = gid >> 10;
    const int row = gid & 1023;
    const int b = bh / NH, h = bh % NH;
    const int bh_u = __builtin_amdgcn_readfirstlane(bh);
    const int b_u = bh_u / NH, h_u = bh_u % NH;

    const float mq = MF[b * NT + row];
    const float De = __fadd_rn(D[(size_t)bh * NT + row], EPS32);  // np: sum+eps

    const float4* qp = (const float4*)&QA[((size_t)(b * NT + row)) * ND + h * 64];
    QLOADALL

    float4 oo0 = {0,0,0,0}, oo1 = {0,0,0,0}, oo2 = {0,0,0,0}, oo3 = {0,0,0,0},
           oo4 = {0,0,0,0}, oo5 = {0,0,0,0}, oo6 = {0,0,0,0}, oo7 = {0,0,0,0},
           oo8 = {0,0,0,0}, oo9 = {0,0,0,0}, oo10 = {0,0,0,0}, oo11 = {0,0,0,0},
           oo12 = {0,0,0,0}, oo13 = {0,0,0,0}, oo14 = {0,0,0,0}, oo15 = {0,0,0,0};

    // K: per-thread (vector/VGPR) base.  V, MF: wave-uniform (scalar/SGPR).
    const float* Kb = &K[((size_t)(b * NT)) * ND + h * 64];
    const float* Vb = &V[((size_t)(b_u * NT)) * ND + h_u * 64];
    const float* MFb = &MF[b_u * NT];

    for (int s = 0; s < NT; s++) {
        const float4* kp = (const float4*)(Kb + (size_t)s * ND);
        KLOADALL
        DOT16(dt)
        float sc = __fmul_rn(dt, SCALE32);
        sc = __fmul_rn(sc, MFb[s]);
        sc = __fmul_rn(sc, mq);
        const float p = __fdiv_rn(sc, De);
        const float* vp = Vb + (size_t)s * ND;               // uniform v
        AXPY(0)  AXPY(1)  AXPY(2)  AXPY(3)  AXPY(4)  AXPY(5)  AXPY(6)  AXPY(7)
        AXPY(8)  AXPY(9)  AXPY(10) AXPY(11) AXPY(12) AXPY(13) AXPY(14) AXPY(15)
    }

    float4* op = (float4*)&QA[((size_t)(b * NT + row)) * ND + h * 64];
    op[0] = oo0;   op[1] = oo1;   op[2] = oo2;   op[3] = oo3;
    op[4] = oo4;   op[5] = oo5;   op[6] = oo6;   op[7] = oo7;
    op[8] = oo8;   op[9] = oo9;   op[10] = oo10; op[11] = oo11;
    op[12] = oo12; op[13] = oo13; op[14] = oo14; op[15] = oo15;
}

// ---------------------------------------------------------------------------
// Row norm, numpy-faithful pairwise mean via ONE WAVE per row (unchanged).
// ---------------------------------------------------------------------------
__global__ __launch_bounds__(256) void rownorm_np(
    float* __restrict__ Y, const float* __restrict__ gamma,
    const float* __restrict__ beta)
{
    const int wave = threadIdx.x >> 6, lane = threadIdx.x & 63;
    const int row = blockIdx.x * 4 + wave;
    float* yr = Y + (size_t)row * ND;
    const int c = lane >> 3, j = lane & 7;

    const float* a = yr + c * 96;
    float r = a[j];
#pragma unroll
    for (int i = 1; i < 12; i++) r = __fadd_rn(r, a[i * 8 + j]);

    // j-tree within base-96 block, then c-tree across blocks (bitwise = R9)
    r = __fadd_rn(r, __shfl_xor(r, 1, 64));
    r = __fadd_rn(r, __shfl_xor(r, 2, 64));
    r = __fadd_rn(r, __shfl_xor(r, 4, 64));
    r = __fadd_rn(r, __shfl_xor(r, 8, 64));
    r = __fadd_rn(r, __shfl_xor(r, 16, 64));
    r = __fadd_rn(r, __shfl_xor(r, 32, 64));

    const float m = __fdiv_rn(r, 768.0f);
    const float mpe = __fadd_rn(m, EPS32);

#pragma unroll
    for (int i = 0; i < 12; i++) {
        const int idx = i * 64 + lane;
        const float v = yr[idx];
        float o = __fsub_rn(v, m);
        o = __fmul_rn(gamma[idx], o);
        o = __fdiv_rn(o, mpe);
        o = __fadd_rn(o, beta[idx]);
        yr[idx] = o;
    }
}

// ---------------------------------------------------------------------------
extern "C" void kernel_launch(void* const* d_in, const int* in_sizes, int n_in,
                              void* d_out, int out_size, void* d_ws, size_t ws_size,
                              hipStream_t stream)
{
    (void)in_sizes; (void)n_in; (void)out_size; (void)ws_size;
    const float* x     = (const float*)d_in[0];
    const unsigned char* maskb = (const unsigned char*)d_in[1];
    const float* wq    = (const float*)d_in[2];
    const float* wk    = (const float*)d_in[3];
    const float* wv    = (const float*)d_in[4];
    const float* wf    = (const float*)d_in[5];
    const float* gamma = (const float*)d_in[6];
    const float* beta  = (const float*)d_in[7];

    float* ws = (float*)d_ws;
    float* MF = ws;                             // 8192
    float* D  = MF + BT;                        // 96*1024
    float* Q  = D + (size_t)96 * NT;            // 8192*768 (becomes A)
    float* K  = Q + (size_t)BT * ND;            // 8192*768
    float* V  = K + (size_t)BT * ND;            // 8192*768
    float* Y  = (float*)d_out;                  // total ws: 75.9 MB

    mask_k<<<1, 256, 0, stream>>>(maskb, MF);
    gemmseq<<<dim3(128, 12), 256, 0, stream>>>(x, wq, nullptr, Q);
    gemmseq<<<dim3(128, 12), 256, 0, stream>>>(x, wk, nullptr, K);
    gemmseq<<<dim3(128, 12), 256, 0, stream>>>(x, wv, nullptr, V);
    denom_np<<<768, 128, 0, stream>>>(Q, K, MF, D);
    attn_np<<<768, 128, 0, stream>>>(K, V, D, MF, Q);  // Q -> A
    gemmseq<<<dim3(128, 12), 256, 0, stream>>>(Q, wf, x, Y);
    rownorm_np<<<2048, 256, 0, stream>>>(Y, gamma, beta);
}

// Round 7
// 2329.176 us; speedup vs baseline: 2.8552x; 2.8552x over previous
//
#include <hip/hip_runtime.h>

// Problem constants
#define NB 8
#define NT 1024
#define ND 768     // = 12*64
#define NH 12
#define NU 64
#define BT (NB*NT)   // 8192
#define SCALE32 ((float)0.03608439182435161)  // fp32(768^-0.5)
#define EPS32 1e-7f

// ---------------------------------------------------------------------------
// numpy baseline-SIMD (SSE2, no FMA) einsum dot over 64 contiguous elements:
// 4 accumulators stride-4, separate mul/add (rounded each), reduce
// (r0+r2)+(r1+r3). __f*_rn blocks hipcc contraction. BITWISE-IDENTICAL.
// b may point to LDS (inlined -> ds_read broadcasts when addr is uniform).
// ---------------------------------------------------------------------------
__device__ __forceinline__ float dot64_np(const float* a, const float* b)
{
    float r[4];
#pragma unroll
    for (int j = 0; j < 4; j++) r[j] = __fmul_rn(a[j], b[j]);
#pragma unroll
    for (int i = 1; i < 16; i++)
#pragma unroll
        for (int j = 0; j < 4; j++)
            r[j] = __fadd_rn(r[j], __fmul_rn(a[i * 4 + j], b[i * 4 + j]));
    return __fadd_rn(__fadd_rn(r[0], r[2]), __fadd_rn(r[1], r[3]));
}

// ---------------------------------------------------------------------------
// Mask decode with byte/int32 layout sniff (mask is all-ones in practice).
// ---------------------------------------------------------------------------
__global__ __launch_bounds__(256) void mask_k(
    const unsigned char* __restrict__ mb, float* __restrict__ mf)
{
    __shared__ int cntOff, cntAll;
    if (threadIdx.x == 0) { cntOff = 0; cntAll = 0; }
    __syncthreads();
    int lo = 0, la = 0;
    for (int i = threadIdx.x; i < BT; i += 256)
        if (mb[i] != 0) { la++; if ((i & 3) != 0) lo++; }
    atomicAdd(&cntOff, lo);
    atomicAdd(&cntAll, la);
    __syncthreads();
    const bool int32mode = (cntOff == 0) && (cntAll != 0);
    if (int32mode) {
        const int* mi = (const int*)mb;
        for (int i = threadIdx.x; i < BT; i += 256)
            mf[i] = (mi[i] != 0) ? 1.f : 0.f;
    } else {
        for (int i = threadIdx.x; i < BT; i += 256)
            mf[i] = (mb[i] != 0) ? 1.f : 0.f;
    }
}

// ---------------------------------------------------------------------------
// OpenBLAS-mimic sgemm: C = A[8192x768] @ W[768x768] (+R elementwise after).
// kc=384 panel split preserved bitwise. grid (128,12). Unchanged from R2.
// ---------------------------------------------------------------------------
__global__ __launch_bounds__(256) void gemmseq(
    const float* __restrict__ A, const float* __restrict__ W,
    const float* __restrict__ R, float* __restrict__ C)
{
    __shared__ float sA[64][68];   // [k][m], transposed, pad 68 (16B-aligned rows)
    __shared__ float sB[64][68];   // [k][n]

    const int t = threadIdx.x;
    const int mbase = blockIdx.x * 64;
    const int nbase = blockIdx.y * 64;
    const int m0 = (t >> 4) * 4;
    const int n0 = (t & 15) * 4;

    float acc[4][4], accA[4][4];
#pragma unroll
    for (int i = 0; i < 4; i++)
#pragma unroll
        for (int j = 0; j < 4; j++) { acc[i][j] = 0.f; accA[i][j] = 0.f; }

    for (int k0 = 0; k0 < 768; k0 += 64) {
        __syncthreads();
#pragma unroll
        for (int i = 0; i < 4; i++) {
            const int idx = t + i * 256;          // 0..1023
            const int mr = idx >> 4;              // 0..63
            const int k4 = (idx & 15) * 4;        // 0..60
            const float4 a4 = *(const float4*)&A[(size_t)(mbase + mr) * 768 + k0 + k4];
            sA[k4 + 0][mr] = a4.x;
            sA[k4 + 1][mr] = a4.y;
            sA[k4 + 2][mr] = a4.z;
            sA[k4 + 3][mr] = a4.w;
            *(float4*)&sB[mr][k4] =
                *(const float4*)&W[(size_t)(k0 + mr) * 768 + nbase + k4];
        }
        __syncthreads();

        for (int kk = 0; kk < 64; kk++) {
            float av[4], bv[4];
            *(float4*)&av[0] = *(const float4*)&sA[kk][m0];
            *(float4*)&bv[0] = *(const float4*)&sB[kk][n0];
#pragma unroll
            for (int i = 0; i < 4; i++)
#pragma unroll
                for (int j = 0; j < 4; j++)
                    acc[i][j] = fmaf(av[i], bv[j], acc[i][j]);
        }

        if (k0 + 64 == 384) {   // end of first kc panel (OpenBLAS kc=384)
#pragma unroll
            for (int i = 0; i < 4; i++)
#pragma unroll
                for (int j = 0; j < 4; j++) {
                    accA[i][j] = acc[i][j];
                    acc[i][j] = 0.f;
                }
        }
    }

#pragma unroll
    for (int i = 0; i < 4; i++)
#pragma unroll
        for (int j = 0; j < 4; j++) {
            const size_t idx = (size_t)(mbase + m0 + i) * 768 + nbase + n0 + j;
            float o = __fadd_rn(accA[i][j], acc[i][j]);  // C = panel0 + panel1
            if (R) o = __fadd_rn(o, R[idx]);             // np: out = tmp + x
            C[idx] = o;
        }
}

// ---------------------------------------------------------------------------
// Denominator: one THREAD per row (R2 structure). K staged in LDS tiles of
// 64 rows (coalesced global loads, L2-hit via XCD swizzle); inner dot reads
// are same-address LDS broadcasts (conflict-free) — frees the SGPR file
// that R2 thrashed. q stays qr[64] exactly as R2 (proven codegen).
// Chain structure = flat ascending-s loop: chain j=s&7 of block c=s>>7,
// init when (s&127)<8, Bi[c] finalized at odd tile boundary — op-for-op
// identical to the serial R9 order. grid 768 x 128, XCD-swizzled.
// ---------------------------------------------------------------------------
__global__ __launch_bounds__(128) void denom_np(
    const float* __restrict__ Q, const float* __restrict__ K,
    const float* __restrict__ MF, float* __restrict__ D)
{
    __shared__ float sK[64][68];

    const int bid = blockIdx.x;
    const int lb  = (bid & 7) * 96 + (bid >> 3);     // XCD-grouped logical id
    const int gid = lb * 128 + threadIdx.x;          // 0..98303
    const int bh = gid >> 10;                        // uniform per block
    const int row = gid & 1023;
    const int b = bh / NH, h = bh % NH;
    const int bh_u = __builtin_amdgcn_readfirstlane(bh);
    const int b_u = bh_u / NH;

    const float mq = MF[b * NT + row];

    float qr[64];
    const float4* qp = (const float4*)&Q[((size_t)(b * NT + row)) * ND + h * 64];
#pragma unroll
    for (int i = 0; i < 16; i++) *(float4*)&qr[i * 4] = qp[i];

    const float* Kg = &K[((size_t)(b * NT)) * ND + h * 64];
    const float* MFb = &MF[b_u * NT];                // scalar path

    float b8[8], Bi[8];

    for (int tile = 0; tile < 16; tile++) {
        __syncthreads();
#pragma unroll
        for (int i = 0; i < 8; i++) {
            const int idx = i * 128 + threadIdx.x;   // 0..1023
            const int r = idx >> 4;                  // 0..63
            const int c4 = (idx & 15) * 4;           // 0..60
            *(float4*)&sK[r][c4] =
                *(const float4*)&Kg[(size_t)(tile * 64 + r) * ND + c4];
        }
        __syncthreads();

        for (int ss = 0; ss < 64; ss++) {
            const int s = tile * 64 + ss;
            const float dt = dot64_np(qr, &sK[ss][0]);   // LDS broadcast
            float sc = __fmul_rn(dt, SCALE32);
            sc = __fmul_rn(sc, MFb[s]);
            sc = __fmul_rn(sc, mq);
            const int j = s & 7;
            if ((s & 127) < 8) b8[j] = sc;
            else               b8[j] = __fadd_rn(b8[j], sc);
        }

        if (tile & 1) {   // completed base-128 block c = tile>>1
            Bi[tile >> 1] = __fadd_rn(
                __fadd_rn(__fadd_rn(b8[0], b8[1]), __fadd_rn(b8[2], b8[3])),
                __fadd_rn(__fadd_rn(b8[4], b8[5]), __fadd_rn(b8[6], b8[7])));
        }
    }

    D[(size_t)bh * NT + row] = __fadd_rn(
        __fadd_rn(__fadd_rn(Bi[0], Bi[1]), __fadd_rn(Bi[2], Bi[3])),
        __fadd_rn(__fadd_rn(Bi[4], Bi[5]), __fadd_rn(Bi[6], Bi[7])));
}

// ---------------------------------------------------------------------------
// Attention out: one THREAD per row (R2 structure). K AND V staged in LDS
// tiles of 64 rows; inner K/V reads are same-address broadcasts on the LDS
// pipe (overlaps VALU), SGPR file freed entirely. q = qr[64], o = o[64]
// exactly as R2 (VGPR 72 codegen proven). Score sequence and o[j] chains
// over ascending s bitwise-identical to R9. Self-aliased QA (row's q read
// fully before any write; only own thread touches the row).
// grid 768 x 128, XCD-swizzled. LDS 34.8 KB (3 blocks/CU fits 160 KB).
// ---------------------------------------------------------------------------
__global__ __launch_bounds__(128) void attn_np(
    const float* __restrict__ K, const float* __restrict__ V,
    const float* __restrict__ D, const float* __restrict__ MF,
    float* __restrict__ QA)   // in: Q, out: A (self-aliased per row)
{
    __shared__ float sK[64][68];
    __shared__ float sV[64][68];

    const int bid = blockIdx.x;
    const int lb  = (bid & 7) * 96 + (bid >> 3);     // XCD-grouped logical id
    const int gid = lb * 128 + threadIdx.x;
    const int bh = gid >> 10;
    const int row = gid & 1023;
    const int b = bh / NH, h = bh % NH;
    const int bh_u = __builtin_amdgcn_readfirstlane(bh);
    const int b_u = bh_u / NH;

    const float mq = MF[b * NT + row];
    const float De = __fadd_rn(D[(size_t)bh * NT + row], EPS32);  // np: sum+eps

    float qr[64];
    const float4* qp = (const float4*)&QA[((size_t)(b * NT + row)) * ND + h * 64];
#pragma unroll
    for (int i = 0; i < 16; i++) *(float4*)&qr[i * 4] = qp[i];

    float o[64];
#pragma unroll
    for (int j = 0; j < 64; j++) o[j] = 0.f;

    const float* Kg = &K[((size_t)(b * NT)) * ND + h * 64];
    const float* Vg = &V[((size_t)(b * NT)) * ND + h * 64];
    const float* MFb = &MF[b_u * NT];

    for (int tile = 0; tile < 16; tile++) {
        __syncthreads();
#pragma unroll
        for (int i = 0; i < 8; i++) {
            const int idx = i * 128 + threadIdx.x;   // 0..1023
            const int r = idx >> 4;                  // 0..63
            const int c4 = (idx & 15) * 4;           // 0..60
            const size_t goff = (size_t)(tile * 64 + r) * ND + c4;
            *(float4*)&sK[r][c4] = *(const float4*)&Kg[goff];
            *(float4*)&sV[r][c4] = *(const float4*)&Vg[goff];
        }
        __syncthreads();

        for (int ss = 0; ss < 64; ss++) {
            const int s = tile * 64 + ss;
            const float dt = dot64_np(qr, &sK[ss][0]);   // LDS broadcast
            float sc = __fmul_rn(dt, SCALE32);
            sc = __fmul_rn(sc, MFb[s]);
            sc = __fmul_rn(sc, mq);
            const float p = __fdiv_rn(sc, De);
            const float* vp = &sV[ss][0];                // LDS broadcast
#pragma unroll
            for (int j = 0; j < 64; j++)
                o[j] = __fadd_rn(o[j], __fmul_rn(p, vp[j]));  // np SSE2 axpy
        }
    }

    float4* op = (float4*)&QA[((size_t)(b * NT + row)) * ND + h * 64];
#pragma unroll
    for (int i = 0; i < 16; i++) op[i] = *(float4*)&o[i * 4];
}

// ---------------------------------------------------------------------------
// Row norm, numpy-faithful pairwise mean via ONE WAVE per row (unchanged).
// ---------------------------------------------------------------------------
__global__ __launch_bounds__(256) void rownorm_np(
    float* __restrict__ Y, const float* __restrict__ gamma,
    const float* __restrict__ beta)
{
    const int wave = threadIdx.x >> 6, lane = threadIdx.x & 63;
    const int row = blockIdx.x * 4 + wave;
    float* yr = Y + (size_t)row * ND;
    const int c = lane >> 3, j = lane & 7;

    const float* a = yr + c * 96;
    float r = a[j];
#pragma unroll
    for (int i = 1; i < 12; i++) r = __fadd_rn(r, a[i * 8 + j]);

    // j-tree within base-96 block, then c-tree across blocks (bitwise = R9)
    r = __fadd_rn(r, __shfl_xor(r, 1, 64));
    r = __fadd_rn(r, __shfl_xor(r, 2, 64));
    r = __fadd_rn(r, __shfl_xor(r, 4, 64));
    r = __fadd_rn(r, __shfl_xor(r, 8, 64));
    r = __fadd_rn(r, __shfl_xor(r, 16, 64));
    r = __fadd_rn(r, __shfl_xor(r, 32, 64));

    const float m = __fdiv_rn(r, 768.0f);
    const float mpe = __fadd_rn(m, EPS32);

#pragma unroll
    for (int i = 0; i < 12; i++) {
        const int idx = i * 64 + lane;
        const float v = yr[idx];
        float o = __fsub_rn(v, m);
        o = __fmul_rn(gamma[idx], o);
        o = __fdiv_rn(o, mpe);
        o = __fadd_rn(o, beta[idx]);
        yr[idx] = o;
    }
}

// ---------------------------------------------------------------------------
extern "C" void kernel_launch(void* const* d_in, const int* in_sizes, int n_in,
                              void* d_out, int out_size, void* d_ws, size_t ws_size,
                              hipStream_t stream)
{
    (void)in_sizes; (void)n_in; (void)out_size; (void)ws_size;
    const float* x     = (const float*)d_in[0];
    const unsigned char* maskb = (const unsigned char*)d_in[1];
    const float* wq    = (const float*)d_in[2];
    const float* wk    = (const float*)d_in[3];
    const float* wv    = (const float*)d_in[4];
    const float* wf    = (const float*)d_in[5];
    const float* gamma = (const float*)d_in[6];
    const float* beta  = (const float*)d_in[7];

    float* ws = (float*)d_ws;
    float* MF = ws;                             // 8192
    float* D  = MF + BT;                        // 96*1024
    float* Q  = D + (size_t)96 * NT;            // 8192*768 (becomes A)
    float* K  = Q + (size_t)BT * ND;            // 8192*768
    float* V  = K + (size_t)BT * ND;            // 8192*768
    float* Y  = (float*)d_out;                  // total ws: 75.9 MB

    mask_k<<<1, 256, 0, stream>>>(maskb, MF);
    gemmseq<<<dim3(128, 12), 256, 0, stream>>>(x, wq, nullptr, Q);
    gemmseq<<<dim3(128, 12), 256, 0, stream>>>(x, wk, nullptr, K);
    gemmseq<<<dim3(128, 12), 256, 0, stream>>>(x, wv, nullptr, V);
    denom_np<<<768, 128, 0, stream>>>(Q, K, MF, D);
    attn_np<<<768, 128, 0, stream>>>(K, V, D, MF, Q);  // Q -> A
    gemmseq<<<dim3(128, 12), 256, 0, stream>>>(Q, wf, x, Y);
    rownorm_np<<<2048, 256, 0, stream>>>(Y, gamma, beta);
}